// Round 1
// baseline (1107.742 us; speedup 1.0000x reference)
//
#include <hip/hip_runtime.h>
#include <stdint.h>

// ---------------------------------------------------------------------------
// GCN 3-layer forward:  out = A_hat @ relu(A_hat @ relu(A_hat @ x W0 + b0) W1 + b1) W2 + b2
// A_hat = D^-1/2 (A + I) D^-1/2, applied as:
//   out[c] = dinv[c] * sum_{edges r->c} dinv[r]*h[r] + dinv[c]^2 * h[c] + b
// Pipeline per call: degree hist -> dinv -> exclusive scan -> counting-sort
// edges by destination -> 3x (dense GEMM + sorted gather-aggregate).
// ---------------------------------------------------------------------------

static inline size_t ws_align(size_t x) { return (x + 255) & ~(size_t)255; }

__device__ __forceinline__ int eidx(const void* p, size_t i, int is64) {
  return is64 ? (int)((const long long*)p)[i] : ((const int*)p)[i];
}

// Detect whether edge_index arrived as int64 (little-endian: odd int32 words
// are the zero high halves, since all values < 2^31) or int32.
__global__ void detect_k(const int* ei, int* flag) {
  if (threadIdx.x == 0 && blockIdx.x == 0) {
    int allz = 1;
    for (int i = 1; i < 128; i += 2)
      if (ei[i] != 0) { allz = 0; break; }
    *flag = allz;
  }
}

__global__ void hist_k(const void* ei, const int* __restrict__ flag, int* deg, int E) {
  int is64 = *flag;
  for (int e = blockIdx.x * blockDim.x + threadIdx.x; e < E; e += gridDim.x * blockDim.x) {
    int c = eidx(ei, (size_t)E + e, is64);
    atomicAdd(&deg[c], 1);
  }
}

__global__ void dinv_k(const int* __restrict__ deg, float* __restrict__ dinv, int n) {
  int i = blockIdx.x * blockDim.x + threadIdx.x;
  if (i < n) dinv[i] = rsqrtf((float)deg[i] + 1.0f);  // +1 = self loop
}

// Exclusive scan of deg[0..n) -> offs[0..n], single block of 1024.
__global__ __launch_bounds__(1024) void scan_k(const int* __restrict__ deg, int* __restrict__ offs, int n) {
  __shared__ int sd[1024];
  int t = threadIdx.x;
  int carry = 0;
  for (int base = 0; base < n; base += 1024) {
    int v = (base + t < n) ? deg[base + t] : 0;
    __syncthreads();          // protect sd from previous iteration's readers
    sd[t] = v;
    __syncthreads();
    for (int off = 1; off < 1024; off <<= 1) {
      int x = (t >= off) ? sd[t - off] : 0;
      __syncthreads();
      sd[t] += x;
      __syncthreads();
    }
    if (base + t < n) offs[base + t] = carry + sd[t] - v;  // exclusive
    carry += sd[1023];
  }
  if (t == 0) offs[n] = carry;
}

__global__ void scatter_k(const void* ei, const int* __restrict__ flag,
                          const int* __restrict__ offs, int* cursor,
                          const float* __restrict__ dinv,
                          int* __restrict__ srcs, float* __restrict__ wv, int E) {
  int is64 = *flag;
  for (int e = blockIdx.x * blockDim.x + threadIdx.x; e < E; e += gridDim.x * blockDim.x) {
    int r = eidx(ei, (size_t)e, is64);
    int c = eidx(ei, (size_t)E + e, is64);
    int pos = offs[c] + atomicAdd(&cursor[c], 1);
    srcs[pos] = r;
    wv[pos] = dinv[r];   // precompute dinv[src] so agg has no dependent lookup
  }
}

// Dense H = X @ W, K=128 fixed, M in {128, 64}. Block = M threads (thread ->
// output column), 16 rows per block. X rows loaded as float4; W loads are
// coalesced across lanes and L1-hot (W is 64/32 KB).
template <int M>
__global__ __launch_bounds__(M) void gemm_k(const float* __restrict__ X,
                                            const float* __restrict__ W,
                                            float* __restrict__ H, int N) {
  const int j = threadIdx.x;
  const int r0 = blockIdx.x * 16;
  float acc[16];
#pragma unroll
  for (int r = 0; r < 16; ++r) acc[r] = 0.f;
  const float4* X4 = (const float4*)X;

  if (r0 + 16 <= N) {
#pragma unroll 1
    for (int k4 = 0; k4 < 32; ++k4) {
      float4 xv[16];
#pragma unroll
      for (int r = 0; r < 16; ++r) xv[r] = X4[(size_t)(r0 + r) * 32 + k4];
#pragma unroll
      for (int kk = 0; kk < 4; ++kk) {
        float w = W[(size_t)(k4 * 4 + kk) * M + j];
#pragma unroll
        for (int r = 0; r < 16; ++r) {
          float xs = (kk == 0) ? xv[r].x : (kk == 1) ? xv[r].y : (kk == 2) ? xv[r].z : xv[r].w;
          acc[r] = fmaf(xs, w, acc[r]);
        }
      }
    }
#pragma unroll
    for (int r = 0; r < 16; ++r) H[(size_t)(r0 + r) * M + j] = acc[r];
  } else {
    int nv = N - r0;
    if (nv <= 0) return;
    for (int k = 0; k < 128; ++k) {
      float w = W[(size_t)k * M + j];
      for (int r = 0; r < nv; ++r)
        acc[r] = fmaf(X[(size_t)(r0 + r) * 128 + k], w, acc[r]);
    }
    for (int r = 0; r < nv; ++r) H[(size_t)(r0 + r) * M + j] = acc[r];
  }
}

// Aggregate for D=128: one wave per node, float2 per lane (64 lanes * 2 = 128).
__global__ __launch_bounds__(256) void agg128_k(const float* __restrict__ H,
                                                const int* __restrict__ offs,
                                                const int* __restrict__ srcs,
                                                const float* __restrict__ wv,
                                                const float* __restrict__ dinv,
                                                const float* __restrict__ bias,
                                                float* __restrict__ out,
                                                int relu, int N) {
  int wid = threadIdx.x >> 6;
  int lane = threadIdx.x & 63;
  int c = blockIdx.x * 4 + wid;
  if (c >= N) return;
  const float2* H2 = (const float2*)H;
  float ax = 0.f, ay = 0.f;
  int e0 = offs[c], e1 = offs[c + 1];
  int e = e0;
  for (; e + 4 <= e1; e += 4) {
    int s0 = srcs[e], s1 = srcs[e + 1], s2 = srcs[e + 2], s3 = srcs[e + 3];
    float w0 = wv[e], w1 = wv[e + 1], w2 = wv[e + 2], w3 = wv[e + 3];
    float2 v0 = H2[(size_t)s0 * 64 + lane];
    float2 v1 = H2[(size_t)s1 * 64 + lane];
    float2 v2 = H2[(size_t)s2 * 64 + lane];
    float2 v3 = H2[(size_t)s3 * 64 + lane];
    ax = fmaf(w0, v0.x, ax); ay = fmaf(w0, v0.y, ay);
    ax = fmaf(w1, v1.x, ax); ay = fmaf(w1, v1.y, ay);
    ax = fmaf(w2, v2.x, ax); ay = fmaf(w2, v2.y, ay);
    ax = fmaf(w3, v3.x, ax); ay = fmaf(w3, v3.y, ay);
  }
  for (; e < e1; ++e) {
    int s = srcs[e];
    float w = wv[e];
    float2 v = H2[(size_t)s * 64 + lane];
    ax = fmaf(w, v.x, ax); ay = fmaf(w, v.y, ay);
  }
  float dc = dinv[c];
  float2 hc = H2[(size_t)c * 64 + lane];
  float rx = fmaf(dc, ax, dc * dc * hc.x) + bias[lane * 2];
  float ry = fmaf(dc, ay, dc * dc * hc.y) + bias[lane * 2 + 1];
  if (relu) { rx = fmaxf(rx, 0.f); ry = fmaxf(ry, 0.f); }
  float2 res; res.x = rx; res.y = ry;
  ((float2*)out)[(size_t)c * 64 + lane] = res;
}

// Aggregate for D=64: one wave per node, 1 float per lane.
__global__ __launch_bounds__(256) void agg64_k(const float* __restrict__ H,
                                               const int* __restrict__ offs,
                                               const int* __restrict__ srcs,
                                               const float* __restrict__ wv,
                                               const float* __restrict__ dinv,
                                               const float* __restrict__ bias,
                                               float* __restrict__ out,
                                               int relu, int N) {
  int wid = threadIdx.x >> 6;
  int lane = threadIdx.x & 63;
  int c = blockIdx.x * 4 + wid;
  if (c >= N) return;
  float acc = 0.f;
  int e0 = offs[c], e1 = offs[c + 1];
  int e = e0;
  for (; e + 4 <= e1; e += 4) {
    int s0 = srcs[e], s1 = srcs[e + 1], s2 = srcs[e + 2], s3 = srcs[e + 3];
    float w0 = wv[e], w1 = wv[e + 1], w2 = wv[e + 2], w3 = wv[e + 3];
    float v0 = H[(size_t)s0 * 64 + lane];
    float v1 = H[(size_t)s1 * 64 + lane];
    float v2 = H[(size_t)s2 * 64 + lane];
    float v3 = H[(size_t)s3 * 64 + lane];
    acc = fmaf(w0, v0, acc);
    acc = fmaf(w1, v1, acc);
    acc = fmaf(w2, v2, acc);
    acc = fmaf(w3, v3, acc);
  }
  for (; e < e1; ++e) {
    acc = fmaf(wv[e], H[(size_t)srcs[e] * 64 + lane], acc);
  }
  float dc = dinv[c];
  float hc = H[(size_t)c * 64 + lane];
  float r = fmaf(dc, acc, dc * dc * hc) + bias[lane];
  if (relu) r = fmaxf(r, 0.f);
  out[(size_t)c * 64 + lane] = r;
}

extern "C" void kernel_launch(void* const* d_in, const int* in_sizes, int n_in,
                              void* d_out, int out_size, void* d_ws, size_t ws_size,
                              hipStream_t stream) {
  const float* x  = (const float*)d_in[0];
  const void*  ei = d_in[1];
  const float* W0 = (const float*)d_in[2];
  const float* b0 = (const float*)d_in[3];
  const float* W1 = (const float*)d_in[4];
  const float* b1 = (const float*)d_in[5];
  const float* W2 = (const float*)d_in[6];
  const float* b2 = (const float*)d_in[7];
  float* out = (float*)d_out;

  const int n = in_sizes[0] / 128;  // 100000
  const int E = in_sizes[1] / 2;    // 1600000

  char* ws = (char*)d_ws;
  size_t off = 0;
  auto alloc = [&](size_t bytes) { char* p = ws + off; off = ws_align(off + bytes); return p; };
  int*   deg    = (int*)alloc((size_t)n * 4);
  int*   cursor = (int*)alloc((size_t)n * 4);
  int*   offs   = (int*)alloc((size_t)(n + 1) * 4);
  float* dinv   = (float*)alloc((size_t)n * 4);
  int*   flag   = (int*)alloc(4);
  int*   srcs   = (int*)alloc((size_t)E * 4);
  float* wv     = (float*)alloc((size_t)E * 4);
  float* hbuf   = (float*)alloc((size_t)n * 128 * 4);
  float* abuf   = (float*)alloc((size_t)n * 128 * 4);
  (void)ws_size;

  hipMemsetAsync(deg, 0, (size_t)n * 4, stream);
  hipMemsetAsync(cursor, 0, (size_t)n * 4, stream);

  detect_k<<<1, 64, 0, stream>>>((const int*)ei, flag);
  hist_k<<<1024, 256, 0, stream>>>(ei, flag, deg, E);
  dinv_k<<<(n + 255) / 256, 256, 0, stream>>>(deg, dinv, n);
  scan_k<<<1, 1024, 0, stream>>>(deg, offs, n);
  scatter_k<<<1024, 256, 0, stream>>>(ei, flag, offs, cursor, dinv, srcs, wv, E);

  int gemm_blocks = (n + 15) / 16;
  int agg_blocks  = (n + 3) / 4;

  // Layer 0: h = x @ W0 ; act = relu(agg(h) + b0)
  gemm_k<128><<<gemm_blocks, 128, 0, stream>>>(x, W0, hbuf, n);
  agg128_k<<<agg_blocks, 256, 0, stream>>>(hbuf, offs, srcs, wv, dinv, b0, abuf, 1, n);
  // Layer 1
  gemm_k<128><<<gemm_blocks, 128, 0, stream>>>(abuf, W1, hbuf, n);
  agg128_k<<<agg_blocks, 256, 0, stream>>>(hbuf, offs, srcs, wv, dinv, b1, abuf, 1, n);
  // Layer 2 (no relu), writes d_out
  gemm_k<64><<<gemm_blocks, 64, 0, stream>>>(abuf, W2, hbuf, n);
  agg64_k<<<agg_blocks, 256, 0, stream>>>(hbuf, offs, srcs, wv, dinv, b2, out, 0, n);
}

// Round 2
// 715.014 us; speedup vs baseline: 1.5493x; 1.5493x over previous
//
#include <hip/hip_runtime.h>
#include <stdint.h>

// ---------------------------------------------------------------------------
// GCN 3-layer forward:  out = A_hat @ relu(A_hat @ relu(A_hat @ x W0 + b0) W1 + b1) W2 + b2
// A_hat = D^-1/2 (A + I) D^-1/2, applied as:
//   out[c] = dinv[c] * sum_{edges r->c} dinv[r]*h[r] + dinv[c]^2 * h[c] + b
// Pipeline: degree hist -> dinv -> 3-kernel exclusive scan -> counting-sort
// edges by destination (packed (src,w) int2) -> 3x (LDS-tiled SGEMM + gather-agg).
// ---------------------------------------------------------------------------

static inline size_t ws_align(size_t x) { return (x + 255) & ~(size_t)255; }

__device__ __forceinline__ int eidx(const void* p, size_t i, int is64) {
  return is64 ? (int)((const long long*)p)[i] : ((const int*)p)[i];
}

// Detect int64 vs int32 edge_index (little-endian: int64 high words are 0).
__global__ void detect_k(const int* ei, int* flag) {
  if (threadIdx.x == 0 && blockIdx.x == 0) {
    int allz = 1;
    for (int i = 1; i < 128; i += 2)
      if (ei[i] != 0) { allz = 0; break; }
    *flag = allz;
  }
}

__global__ void hist_k(const void* ei, const int* __restrict__ flag, int* deg, int E) {
  int is64 = *flag;
  for (int e = blockIdx.x * blockDim.x + threadIdx.x; e < E; e += gridDim.x * blockDim.x) {
    int c = eidx(ei, (size_t)E + e, is64);
    atomicAdd(&deg[c], 1);
  }
}

__global__ void dinv_k(const int* __restrict__ deg, float* __restrict__ dinv, int n) {
  int i = blockIdx.x * blockDim.x + threadIdx.x;
  if (i < n) dinv[i] = rsqrtf((float)deg[i] + 1.0f);  // +1 = self loop
}

// --- 3-kernel exclusive scan of deg[0..n) -> offs[0..n] --------------------
__global__ __launch_bounds__(1024) void scan1_k(const int* __restrict__ deg,
                                                int* __restrict__ offs,
                                                int* __restrict__ bsum, int n) {
  __shared__ int sd[1024];
  int t = threadIdx.x;
  int gid = blockIdx.x * 1024 + t;
  int v = (gid < n) ? deg[gid] : 0;
  sd[t] = v;
  __syncthreads();
  for (int off = 1; off < 1024; off <<= 1) {
    int x = (t >= off) ? sd[t - off] : 0;
    __syncthreads();
    sd[t] += x;
    __syncthreads();
  }
  if (gid < n) offs[gid] = sd[t] - v;  // exclusive within block
  if (t == 1023) bsum[blockIdx.x] = sd[1023];
}

__global__ __launch_bounds__(128) void scan2_k(const int* __restrict__ bsum,
                                               int* __restrict__ boff, int nb) {
  __shared__ int sd[128];
  int t = threadIdx.x;
  int v = (t < nb) ? bsum[t] : 0;
  sd[t] = v;
  __syncthreads();
  for (int off = 1; off < 128; off <<= 1) {
    int x = (t >= off) ? sd[t - off] : 0;
    __syncthreads();
    sd[t] += x;
    __syncthreads();
  }
  if (t < nb) boff[t] = sd[t] - v;      // exclusive
  if (t == nb - 1) boff[nb] = sd[t];    // grand total
}

__global__ void scan3_k(int* __restrict__ offs, const int* __restrict__ boff,
                        int n, int nb) {
  int gid = blockIdx.x * blockDim.x + threadIdx.x;
  if (gid < n) offs[gid] += boff[gid >> 10];
  if (gid == n) offs[n] = boff[nb];
}

// Counting-sort scatter: edge -> slot sorted by destination; pack (src, dinv[src]).
__global__ void scatter_k(const void* ei, const int* __restrict__ flag,
                          const int* __restrict__ offs, int* cursor,
                          const float* __restrict__ dinv,
                          int2* __restrict__ epk, int E) {
  int is64 = *flag;
  for (int e = blockIdx.x * blockDim.x + threadIdx.x; e < E; e += gridDim.x * blockDim.x) {
    int r = eidx(ei, (size_t)e, is64);
    int c = eidx(ei, (size_t)E + e, is64);
    int pos = offs[c] + atomicAdd(&cursor[c], 1);
    epk[pos] = make_int2(r, __float_as_int(dinv[r]));
  }
}

// --- LDS-tiled SGEMM: H[N x COLS] = X[N x 128] @ W[128 x COLS] -------------
// Block 256 threads, tile ROWS x COLS, K chunked by 32 (Xs transposed).
// Thread computes an 8x8 register tile: 64 FMA per 4 ds_read_b128 (0.5 B/FLOP).
template <int COLS>
__global__ __launch_bounds__(256) void gemm_k(const float* __restrict__ X,
                                              const float* __restrict__ W,
                                              float* __restrict__ H, int N) {
  constexpr int KB = 32;
  constexpr int CG = COLS / 8;        // col groups
  constexpr int RG = 256 / CG;        // row groups
  constexpr int ROWS = RG * 8;        // 128 (COLS=128) or 256 (COLS=64)
  constexpr int XP = ROWS + 4;        // pitch: keeps 16B alignment, breaks bank stride

  __shared__ float Xs[KB][XP];
  __shared__ float Ws[KB][COLS];

  const int tid = threadIdx.x;
  const int cg = tid % CG, rg = tid / CG;
  const int c0 = cg * 8, rr0 = rg * 8;
  const int rowbase = blockIdx.x * ROWS;

  float acc[8][8];
#pragma unroll
  for (int a = 0; a < 8; ++a)
#pragma unroll
    for (int b = 0; b < 8; ++b) acc[a][b] = 0.f;

  for (int k0 = 0; k0 < 128; k0 += KB) {
    __syncthreads();  // protect LDS from previous chunk's readers
    // stage W chunk: KB x COLS
#pragma unroll
    for (int i = tid; i < KB * (COLS / 4); i += 256) {
      int kk = i / (COLS / 4);
      int cc = i % (COLS / 4);
      float4 w = ((const float4*)(W + (size_t)(k0 + kk) * COLS))[cc];
      ((float4*)&Ws[kk][0])[cc] = w;
    }
    // stage X chunk transposed: Xs[k][row]
#pragma unroll
    for (int i = tid; i < ROWS * (KB / 4); i += 256) {
      int rr = i / (KB / 4);
      int k4 = i % (KB / 4);
      int gr = rowbase + rr;
      if (gr >= N) gr = N - 1;  // clamp; stores are guarded
      float4 xv = ((const float4*)(X + (size_t)gr * 128 + k0))[k4];
      Xs[k4 * 4 + 0][rr] = xv.x;
      Xs[k4 * 4 + 1][rr] = xv.y;
      Xs[k4 * 4 + 2][rr] = xv.z;
      Xs[k4 * 4 + 3][rr] = xv.w;
    }
    __syncthreads();
#pragma unroll 2
    for (int k = 0; k < KB; ++k) {
      float4 xa = *(const float4*)&Xs[k][rr0];
      float4 xb = *(const float4*)&Xs[k][rr0 + 4];
      float4 wa = *(const float4*)&Ws[k][c0];
      float4 wb = *(const float4*)&Ws[k][c0 + 4];
      float xr[8] = {xa.x, xa.y, xa.z, xa.w, xb.x, xb.y, xb.z, xb.w};
      float wr[8] = {wa.x, wa.y, wa.z, wa.w, wb.x, wb.y, wb.z, wb.w};
#pragma unroll
      for (int a = 0; a < 8; ++a)
#pragma unroll
        for (int b = 0; b < 8; ++b) acc[a][b] = fmaf(xr[a], wr[b], acc[a][b]);
    }
  }
#pragma unroll
  for (int a = 0; a < 8; ++a) {
    int row = rowbase + rr0 + a;
    if (row < N) {
      float4 o1 = make_float4(acc[a][0], acc[a][1], acc[a][2], acc[a][3]);
      float4 o2 = make_float4(acc[a][4], acc[a][5], acc[a][6], acc[a][7]);
      *(float4*)&H[(size_t)row * COLS + c0] = o1;
      *(float4*)&H[(size_t)row * COLS + c0 + 4] = o2;
    }
  }
}

// Aggregate D=128: one wave per node, float2 per lane.
__global__ __launch_bounds__(256) void agg128_k(const float* __restrict__ H,
                                                const int* __restrict__ offs,
                                                const int2* __restrict__ epk,
                                                const float* __restrict__ dinv,
                                                const float* __restrict__ bias,
                                                float* __restrict__ out,
                                                int relu, int N) {
  int wid = threadIdx.x >> 6;
  int lane = threadIdx.x & 63;
  int c = blockIdx.x * 4 + wid;
  if (c >= N) return;
  const float2* H2 = (const float2*)H;
  float ax = 0.f, ay = 0.f;
  int e0 = offs[c], e1 = offs[c + 1];
  int e = e0;
  for (; e + 4 <= e1; e += 4) {
    int2 p0 = epk[e], p1 = epk[e + 1], p2 = epk[e + 2], p3 = epk[e + 3];
    float2 v0 = H2[(size_t)p0.x * 64 + lane];
    float2 v1 = H2[(size_t)p1.x * 64 + lane];
    float2 v2 = H2[(size_t)p2.x * 64 + lane];
    float2 v3 = H2[(size_t)p3.x * 64 + lane];
    float w0 = __int_as_float(p0.y), w1 = __int_as_float(p1.y);
    float w2 = __int_as_float(p2.y), w3 = __int_as_float(p3.y);
    ax = fmaf(w0, v0.x, ax); ay = fmaf(w0, v0.y, ay);
    ax = fmaf(w1, v1.x, ax); ay = fmaf(w1, v1.y, ay);
    ax = fmaf(w2, v2.x, ax); ay = fmaf(w2, v2.y, ay);
    ax = fmaf(w3, v3.x, ax); ay = fmaf(w3, v3.y, ay);
  }
  for (; e < e1; ++e) {
    int2 p = epk[e];
    float2 v = H2[(size_t)p.x * 64 + lane];
    float w = __int_as_float(p.y);
    ax = fmaf(w, v.x, ax); ay = fmaf(w, v.y, ay);
  }
  float dc = dinv[c];
  float2 hc = H2[(size_t)c * 64 + lane];
  float rx = fmaf(dc, ax, dc * dc * hc.x) + bias[lane * 2];
  float ry = fmaf(dc, ay, dc * dc * hc.y) + bias[lane * 2 + 1];
  if (relu) { rx = fmaxf(rx, 0.f); ry = fmaxf(ry, 0.f); }
  float2 res; res.x = rx; res.y = ry;
  ((float2*)out)[(size_t)c * 64 + lane] = res;
}

// Aggregate D=64: one wave per node, 1 float per lane.
__global__ __launch_bounds__(256) void agg64_k(const float* __restrict__ H,
                                               const int* __restrict__ offs,
                                               const int2* __restrict__ epk,
                                               const float* __restrict__ dinv,
                                               const float* __restrict__ bias,
                                               float* __restrict__ out,
                                               int relu, int N) {
  int wid = threadIdx.x >> 6;
  int lane = threadIdx.x & 63;
  int c = blockIdx.x * 4 + wid;
  if (c >= N) return;
  float acc = 0.f;
  int e0 = offs[c], e1 = offs[c + 1];
  int e = e0;
  for (; e + 4 <= e1; e += 4) {
    int2 p0 = epk[e], p1 = epk[e + 1], p2 = epk[e + 2], p3 = epk[e + 3];
    float v0 = H[(size_t)p0.x * 64 + lane];
    float v1 = H[(size_t)p1.x * 64 + lane];
    float v2 = H[(size_t)p2.x * 64 + lane];
    float v3 = H[(size_t)p3.x * 64 + lane];
    acc = fmaf(__int_as_float(p0.y), v0, acc);
    acc = fmaf(__int_as_float(p1.y), v1, acc);
    acc = fmaf(__int_as_float(p2.y), v2, acc);
    acc = fmaf(__int_as_float(p3.y), v3, acc);
  }
  for (; e < e1; ++e) {
    int2 p = epk[e];
    acc = fmaf(__int_as_float(p.y), H[(size_t)p.x * 64 + lane], acc);
  }
  float dc = dinv[c];
  float hc = H[(size_t)c * 64 + lane];
  float r = fmaf(dc, acc, dc * dc * hc) + bias[lane];
  if (relu) r = fmaxf(r, 0.f);
  out[(size_t)c * 64 + lane] = r;
}

extern "C" void kernel_launch(void* const* d_in, const int* in_sizes, int n_in,
                              void* d_out, int out_size, void* d_ws, size_t ws_size,
                              hipStream_t stream) {
  const float* x  = (const float*)d_in[0];
  const void*  ei = d_in[1];
  const float* W0 = (const float*)d_in[2];
  const float* b0 = (const float*)d_in[3];
  const float* W1 = (const float*)d_in[4];
  const float* b1 = (const float*)d_in[5];
  const float* W2 = (const float*)d_in[6];
  const float* b2 = (const float*)d_in[7];
  float* out = (float*)d_out;

  const int n = in_sizes[0] / 128;  // 100000
  const int E = in_sizes[1] / 2;    // 1600000
  const int nb = (n + 1023) / 1024; // scan blocks (98)

  char* ws = (char*)d_ws;
  size_t off = 0;
  auto alloc = [&](size_t bytes) { char* p = ws + off; off = ws_align(off + bytes); return p; };
  int*   deg    = (int*)alloc((size_t)n * 4);
  int*   cursor = (int*)alloc((size_t)n * 4);
  int*   offs   = (int*)alloc((size_t)(n + 1) * 4);
  float* dinv   = (float*)alloc((size_t)n * 4);
  int*   flag   = (int*)alloc(4);
  int*   bsum   = (int*)alloc((size_t)(nb + 1) * 4);
  int*   boff   = (int*)alloc((size_t)(nb + 1) * 4);
  int2*  epk    = (int2*)alloc((size_t)E * 8);
  float* hbuf   = (float*)alloc((size_t)n * 128 * 4);
  float* abuf   = (float*)alloc((size_t)n * 128 * 4);
  (void)ws_size;

  hipMemsetAsync(deg, 0, (size_t)n * 4, stream);
  hipMemsetAsync(cursor, 0, (size_t)n * 4, stream);

  detect_k<<<1, 64, 0, stream>>>((const int*)ei, flag);
  hist_k<<<1024, 256, 0, stream>>>(ei, flag, deg, E);
  dinv_k<<<(n + 255) / 256, 256, 0, stream>>>(deg, dinv, n);
  scan1_k<<<nb, 1024, 0, stream>>>(deg, offs, bsum, n);
  scan2_k<<<1, 128, 0, stream>>>(bsum, boff, nb);
  scan3_k<<<(n + 256) / 256, 256, 0, stream>>>(offs, boff, n, nb);
  scatter_k<<<1024, 256, 0, stream>>>(ei, flag, offs, cursor, dinv, epk, E);

  int agg_blocks = (n + 3) / 4;

  // Layer 0
  gemm_k<128><<<(n + 127) / 128, 256, 0, stream>>>(x, W0, hbuf, n);
  agg128_k<<<agg_blocks, 256, 0, stream>>>(hbuf, offs, epk, dinv, b0, abuf, 1, n);
  // Layer 1
  gemm_k<128><<<(n + 127) / 128, 256, 0, stream>>>(abuf, W1, hbuf, n);
  agg128_k<<<agg_blocks, 256, 0, stream>>>(hbuf, offs, epk, dinv, b1, abuf, 1, n);
  // Layer 2 (no relu) -> d_out
  gemm_k<64><<<(n + 255) / 256, 256, 0, stream>>>(abuf, W2, hbuf, n);
  agg64_k<<<agg_blocks, 256, 0, stream>>>(hbuf, offs, epk, dinv, b2, out, 0, n);
}

// Round 3
// 612.419 us; speedup vs baseline: 1.8088x; 1.1675x over previous
//
#include <hip/hip_runtime.h>
#include <stdint.h>

// ---------------------------------------------------------------------------
// GCN 3-layer forward:  out = A_hat @ relu(A_hat @ relu(A_hat @ x W0 + b0) W1 + b1) W2 + b2
// A_hat = D^-1/2 (A + I) D^-1/2, applied as:
//   out[c] = dinv[c] * sum_{edges r->c} dinv[r]*h[r] + dinv[c]^2 * h[c] + b
// Pipeline: degree hist -> dinv -> 3-kernel exclusive scan -> counting-sort
// edges by destination (packed (src,w) int2) -> 3x (LDS-tiled SGEMM + gather-agg).
//
// R2 insight: FETCH_SIZE of agg == 8 XCD x sizeof(H): every XCD pulls all of
// H through its L2 (random graph). Only lever is shrinking H -> GEMM emits H
// in bf16 (gather payload only; accumulation + inter-layer activations fp32).
// ---------------------------------------------------------------------------

static inline size_t ws_align(size_t x) { return (x + 255) & ~(size_t)255; }

__device__ __forceinline__ int eidx(const void* p, size_t i, int is64) {
  return is64 ? (int)((const long long*)p)[i] : ((const int*)p)[i];
}

__device__ __forceinline__ uint16_t f2bf(float f) {  // RNE float->bf16
  uint32_t u = __float_as_uint(f);
  u += 0x7fffu + ((u >> 16) & 1u);
  return (uint16_t)(u >> 16);
}

// Detect int64 vs int32 edge_index (little-endian: int64 high words are 0).
__global__ void detect_k(const int* ei, int* flag) {
  if (threadIdx.x == 0 && blockIdx.x == 0) {
    int allz = 1;
    for (int i = 1; i < 128; i += 2)
      if (ei[i] != 0) { allz = 0; break; }
    *flag = allz;
  }
}

__global__ void hist_k(const void* ei, const int* __restrict__ flag, int* deg, int E) {
  int is64 = *flag;
  for (int e = blockIdx.x * blockDim.x + threadIdx.x; e < E; e += gridDim.x * blockDim.x) {
    int c = eidx(ei, (size_t)E + e, is64);
    atomicAdd(&deg[c], 1);
  }
}

__global__ void dinv_k(const int* __restrict__ deg, float* __restrict__ dinv, int n) {
  int i = blockIdx.x * blockDim.x + threadIdx.x;
  if (i < n) dinv[i] = rsqrtf((float)deg[i] + 1.0f);  // +1 = self loop
}

// --- 3-kernel exclusive scan of deg[0..n) -> offs[0..n] --------------------
__global__ __launch_bounds__(1024) void scan1_k(const int* __restrict__ deg,
                                                int* __restrict__ offs,
                                                int* __restrict__ bsum, int n) {
  __shared__ int sd[1024];
  int t = threadIdx.x;
  int gid = blockIdx.x * 1024 + t;
  int v = (gid < n) ? deg[gid] : 0;
  sd[t] = v;
  __syncthreads();
  for (int off = 1; off < 1024; off <<= 1) {
    int x = (t >= off) ? sd[t - off] : 0;
    __syncthreads();
    sd[t] += x;
    __syncthreads();
  }
  if (gid < n) offs[gid] = sd[t] - v;  // exclusive within block
  if (t == 1023) bsum[blockIdx.x] = sd[1023];
}

__global__ __launch_bounds__(128) void scan2_k(const int* __restrict__ bsum,
                                               int* __restrict__ boff, int nb) {
  __shared__ int sd[128];
  int t = threadIdx.x;
  int v = (t < nb) ? bsum[t] : 0;
  sd[t] = v;
  __syncthreads();
  for (int off = 1; off < 128; off <<= 1) {
    int x = (t >= off) ? sd[t - off] : 0;
    __syncthreads();
    sd[t] += x;
    __syncthreads();
  }
  if (t < nb) boff[t] = sd[t] - v;      // exclusive
  if (t == nb - 1) boff[nb] = sd[t];    // grand total
}

__global__ void scan3_k(int* __restrict__ offs, const int* __restrict__ boff,
                        int n, int nb) {
  int gid = blockIdx.x * blockDim.x + threadIdx.x;
  if (gid < n) offs[gid] += boff[gid >> 10];
  if (gid == n) offs[n] = boff[nb];
}

// Counting-sort scatter: edge -> slot sorted by destination; pack (src, dinv[src]).
__global__ void scatter_k(const void* ei, const int* __restrict__ flag,
                          const int* __restrict__ offs, int* cursor,
                          const float* __restrict__ dinv,
                          int2* __restrict__ epk, int E) {
  int is64 = *flag;
  for (int e = blockIdx.x * blockDim.x + threadIdx.x; e < E; e += gridDim.x * blockDim.x) {
    int r = eidx(ei, (size_t)e, is64);
    int c = eidx(ei, (size_t)E + e, is64);
    int pos = offs[c] + atomicAdd(&cursor[c], 1);
    epk[pos] = make_int2(r, __float_as_int(dinv[r]));
  }
}

// --- LDS-tiled SGEMM: H[N x COLS](bf16) = X[N x 128](f32) @ W[128 x COLS] --
// Block 256 threads, tile ROWS x COLS, K chunked by 32 (Xs transposed).
// Thread computes an 8x8 register tile: 64 FMA per 4 ds_read_b128.
template <int COLS>
__global__ __launch_bounds__(256) void gemm_k(const float* __restrict__ X,
                                              const float* __restrict__ W,
                                              uint16_t* __restrict__ H, int N) {
  constexpr int KB = 32;
  constexpr int CG = COLS / 8;        // col groups
  constexpr int RG = 256 / CG;        // row groups
  constexpr int ROWS = RG * 8;        // 128 (COLS=128) or 256 (COLS=64)
  constexpr int XP = ROWS + 4;        // pitch: keeps 16B alignment, breaks bank stride

  __shared__ float Xs[KB][XP];
  __shared__ float Ws[KB][COLS];

  const int tid = threadIdx.x;
  const int cg = tid % CG, rg = tid / CG;
  const int c0 = cg * 8, rr0 = rg * 8;
  const int rowbase = blockIdx.x * ROWS;

  float acc[8][8];
#pragma unroll
  for (int a = 0; a < 8; ++a)
#pragma unroll
    for (int b = 0; b < 8; ++b) acc[a][b] = 0.f;

  for (int k0 = 0; k0 < 128; k0 += KB) {
    __syncthreads();  // protect LDS from previous chunk's readers
#pragma unroll
    for (int i = tid; i < KB * (COLS / 4); i += 256) {
      int kk = i / (COLS / 4);
      int cc = i % (COLS / 4);
      float4 w = ((const float4*)(W + (size_t)(k0 + kk) * COLS))[cc];
      ((float4*)&Ws[kk][0])[cc] = w;
    }
#pragma unroll
    for (int i = tid; i < ROWS * (KB / 4); i += 256) {
      int rr = i / (KB / 4);
      int k4 = i % (KB / 4);
      int gr = rowbase + rr;
      if (gr >= N) gr = N - 1;  // clamp; stores are guarded
      float4 xv = ((const float4*)(X + (size_t)gr * 128 + k0))[k4];
      Xs[k4 * 4 + 0][rr] = xv.x;
      Xs[k4 * 4 + 1][rr] = xv.y;
      Xs[k4 * 4 + 2][rr] = xv.z;
      Xs[k4 * 4 + 3][rr] = xv.w;
    }
    __syncthreads();
#pragma unroll 2
    for (int k = 0; k < KB; ++k) {
      float4 xa = *(const float4*)&Xs[k][rr0];
      float4 xb = *(const float4*)&Xs[k][rr0 + 4];
      float4 wa = *(const float4*)&Ws[k][c0];
      float4 wb = *(const float4*)&Ws[k][c0 + 4];
      float xr[8] = {xa.x, xa.y, xa.z, xa.w, xb.x, xb.y, xb.z, xb.w};
      float wr[8] = {wa.x, wa.y, wa.z, wa.w, wb.x, wb.y, wb.z, wb.w};
#pragma unroll
      for (int a = 0; a < 8; ++a)
#pragma unroll
        for (int b = 0; b < 8; ++b) acc[a][b] = fmaf(xr[a], wr[b], acc[a][b]);
    }
  }
#pragma unroll
  for (int a = 0; a < 8; ++a) {
    int row = rowbase + rr0 + a;
    if (row < N) {
      uint32_t p[4];
#pragma unroll
      for (int q = 0; q < 4; ++q)
        p[q] = (uint32_t)f2bf(acc[a][2 * q]) | ((uint32_t)f2bf(acc[a][2 * q + 1]) << 16);
      uint4 ov = make_uint4(p[0], p[1], p[2], p[3]);
      *(uint4*)&H[(size_t)row * COLS + c0] = ov;  // c0 mult of 8 -> 16B aligned
    }
  }
}

// Aggregate D=128 from bf16 H: one wave per node, 1 uint (2 bf16) per lane.
__global__ __launch_bounds__(256) void agg128_k(const uint32_t* __restrict__ H2,
                                                const int* __restrict__ offs,
                                                const int2* __restrict__ epk,
                                                const float* __restrict__ dinv,
                                                const float* __restrict__ bias,
                                                float* __restrict__ out,
                                                int relu, int N) {
  int wid = threadIdx.x >> 6;
  int lane = threadIdx.x & 63;
  int c = blockIdx.x * 4 + wid;
  if (c >= N) return;
  float ax = 0.f, ay = 0.f;
  int e0 = offs[c], e1 = offs[c + 1];
  int e = e0;
  for (; e + 4 <= e1; e += 4) {
    int2 p0 = epk[e], p1 = epk[e + 1], p2 = epk[e + 2], p3 = epk[e + 3];
    uint32_t v0 = H2[(size_t)p0.x * 64 + lane];
    uint32_t v1 = H2[(size_t)p1.x * 64 + lane];
    uint32_t v2 = H2[(size_t)p2.x * 64 + lane];
    uint32_t v3 = H2[(size_t)p3.x * 64 + lane];
    float w0 = __int_as_float(p0.y), w1 = __int_as_float(p1.y);
    float w2 = __int_as_float(p2.y), w3 = __int_as_float(p3.y);
    ax = fmaf(w0, __uint_as_float(v0 << 16), ax); ay = fmaf(w0, __uint_as_float(v0 & 0xffff0000u), ay);
    ax = fmaf(w1, __uint_as_float(v1 << 16), ax); ay = fmaf(w1, __uint_as_float(v1 & 0xffff0000u), ay);
    ax = fmaf(w2, __uint_as_float(v2 << 16), ax); ay = fmaf(w2, __uint_as_float(v2 & 0xffff0000u), ay);
    ax = fmaf(w3, __uint_as_float(v3 << 16), ax); ay = fmaf(w3, __uint_as_float(v3 & 0xffff0000u), ay);
  }
  for (; e < e1; ++e) {
    int2 p = epk[e];
    uint32_t v = H2[(size_t)p.x * 64 + lane];
    float w = __int_as_float(p.y);
    ax = fmaf(w, __uint_as_float(v << 16), ax);
    ay = fmaf(w, __uint_as_float(v & 0xffff0000u), ay);
  }
  float dc = dinv[c];
  uint32_t hv = H2[(size_t)c * 64 + lane];
  float rx = fmaf(dc, ax, dc * dc * __uint_as_float(hv << 16)) + bias[lane * 2];
  float ry = fmaf(dc, ay, dc * dc * __uint_as_float(hv & 0xffff0000u)) + bias[lane * 2 + 1];
  if (relu) { rx = fmaxf(rx, 0.f); ry = fmaxf(ry, 0.f); }
  float2 res; res.x = rx; res.y = ry;
  ((float2*)out)[(size_t)c * 64 + lane] = res;
}

// Aggregate D=64 from bf16 H: one wave per node, 1 ushort per lane.
__global__ __launch_bounds__(256) void agg64_k(const uint16_t* __restrict__ H,
                                               const int* __restrict__ offs,
                                               const int2* __restrict__ epk,
                                               const float* __restrict__ dinv,
                                               const float* __restrict__ bias,
                                               float* __restrict__ out,
                                               int relu, int N) {
  int wid = threadIdx.x >> 6;
  int lane = threadIdx.x & 63;
  int c = blockIdx.x * 4 + wid;
  if (c >= N) return;
  float acc = 0.f;
  int e0 = offs[c], e1 = offs[c + 1];
  int e = e0;
  for (; e + 4 <= e1; e += 4) {
    int2 p0 = epk[e], p1 = epk[e + 1], p2 = epk[e + 2], p3 = epk[e + 3];
    uint32_t v0 = H[(size_t)p0.x * 64 + lane];
    uint32_t v1 = H[(size_t)p1.x * 64 + lane];
    uint32_t v2 = H[(size_t)p2.x * 64 + lane];
    uint32_t v3 = H[(size_t)p3.x * 64 + lane];
    acc = fmaf(__int_as_float(p0.y), __uint_as_float(v0 << 16), acc);
    acc = fmaf(__int_as_float(p1.y), __uint_as_float(v1 << 16), acc);
    acc = fmaf(__int_as_float(p2.y), __uint_as_float(v2 << 16), acc);
    acc = fmaf(__int_as_float(p3.y), __uint_as_float(v3 << 16), acc);
  }
  for (; e < e1; ++e) {
    int2 p = epk[e];
    uint32_t v = H[(size_t)p.x * 64 + lane];
    acc = fmaf(__int_as_float(p.y), __uint_as_float(v << 16), acc);
  }
  float dc = dinv[c];
  uint32_t hv = H[(size_t)c * 64 + lane];
  float r = fmaf(dc, acc, dc * dc * __uint_as_float(hv << 16)) + bias[lane];
  if (relu) r = fmaxf(r, 0.f);
  out[(size_t)c * 64 + lane] = r;
}

extern "C" void kernel_launch(void* const* d_in, const int* in_sizes, int n_in,
                              void* d_out, int out_size, void* d_ws, size_t ws_size,
                              hipStream_t stream) {
  const float* x  = (const float*)d_in[0];
  const void*  ei = d_in[1];
  const float* W0 = (const float*)d_in[2];
  const float* b0 = (const float*)d_in[3];
  const float* W1 = (const float*)d_in[4];
  const float* b1 = (const float*)d_in[5];
  const float* W2 = (const float*)d_in[6];
  const float* b2 = (const float*)d_in[7];
  float* out = (float*)d_out;

  const int n = in_sizes[0] / 128;  // 100000
  const int E = in_sizes[1] / 2;    // 1600000
  const int nb = (n + 1023) / 1024; // scan blocks (98)

  char* ws = (char*)d_ws;
  size_t off = 0;
  auto alloc = [&](size_t bytes) { char* p = ws + off; off = ws_align(off + bytes); return p; };
  int*      deg    = (int*)alloc((size_t)n * 4);
  int*      cursor = (int*)alloc((size_t)n * 4);
  int*      offs   = (int*)alloc((size_t)(n + 1) * 4);
  float*    dinv   = (float*)alloc((size_t)n * 4);
  int*      flag   = (int*)alloc(4);
  int*      bsum   = (int*)alloc((size_t)(nb + 1) * 4);
  int*      boff   = (int*)alloc((size_t)(nb + 1) * 4);
  int2*     epk    = (int2*)alloc((size_t)E * 8);
  uint16_t* hbuf   = (uint16_t*)alloc((size_t)n * 128 * 2);  // bf16 gather payload
  float*    abuf   = (float*)alloc((size_t)n * 128 * 4);     // fp32 activations
  (void)ws_size;

  hipMemsetAsync(deg, 0, (size_t)n * 4, stream);
  hipMemsetAsync(cursor, 0, (size_t)n * 4, stream);

  detect_k<<<1, 64, 0, stream>>>((const int*)ei, flag);
  hist_k<<<1024, 256, 0, stream>>>(ei, flag, deg, E);
  dinv_k<<<(n + 255) / 256, 256, 0, stream>>>(deg, dinv, n);
  scan1_k<<<nb, 1024, 0, stream>>>(deg, offs, bsum, n);
  scan2_k<<<1, 128, 0, stream>>>(bsum, boff, nb);
  scan3_k<<<(n + 256) / 256, 256, 0, stream>>>(offs, boff, n, nb);
  scatter_k<<<1024, 256, 0, stream>>>(ei, flag, offs, cursor, dinv, epk, E);

  int agg_blocks = (n + 3) / 4;

  // Layer 0
  gemm_k<128><<<(n + 127) / 128, 256, 0, stream>>>(x, W0, hbuf, n);
  agg128_k<<<agg_blocks, 256, 0, stream>>>((const uint32_t*)hbuf, offs, epk, dinv, b0, abuf, 1, n);
  // Layer 1
  gemm_k<128><<<(n + 127) / 128, 256, 0, stream>>>(abuf, W1, hbuf, n);
  agg128_k<<<agg_blocks, 256, 0, stream>>>((const uint32_t*)hbuf, offs, epk, dinv, b1, abuf, 1, n);
  // Layer 2 (no relu) -> d_out (fp32)
  gemm_k<64><<<(n + 255) / 256, 256, 0, stream>>>(abuf, W2, hbuf, n);
  agg64_k<<<agg_blocks, 256, 0, stream>>>(hbuf, offs, epk, dinv, b2, out, 0, n);
}

// Round 4
// 537.015 us; speedup vs baseline: 2.0628x; 1.1404x over previous
//
#include <hip/hip_runtime.h>
#include <stdint.h>

// ---------------------------------------------------------------------------
// GCN 3-layer forward:  out = A_hat @ relu(A_hat @ relu(A_hat @ x W0 + b0) W1 + b1) W2 + b2
// A_hat = D^-1/2 (A + I) D^-1/2, applied as:
//   out[c] = dinv[c] * sum_{edges r->c} dinv[r]*h[r] + dinv[c]^2 * h[c] + b
//
// R2 insight: agg FETCH == 8 XCD x sizeof(H) (random graph) -> H stored bf16.
// R3 insight: one-shot counting-sort scatter was transaction-bound and caused
//   64B partial-line writeback per edge (cross-XCD). Replaced with bucketed
//   two-pass sort: LDS-binned coalesced partition (passB) + per-bucket
//   placement where each output region is owned by ONE workgroup (passC).
//   deg/offs now derived per-bucket in LDS (passC0) -> no global hist, no
//   100K-wide scans.
// Bucket = 512 consecutive dest nodes (shift 9); NB = ceil(n/512) <= 256.
// ---------------------------------------------------------------------------

static inline size_t ws_align(size_t x) { return (x + 255) & ~(size_t)255; }

__device__ __forceinline__ int eidx(const void* p, size_t i, int is64) {
  return is64 ? (int)((const long long*)p)[i] : ((const int*)p)[i];
}

__device__ __forceinline__ uint16_t f2bf(float f) {  // RNE float->bf16
  uint32_t u = __float_as_uint(f);
  u += 0x7fffu + ((u >> 16) & 1u);
  return (uint16_t)(u >> 16);
}

// Detect int64 vs int32 edge_index (little-endian: int64 high words are 0).
__global__ void detect_k(const int* ei, int* flag) {
  if (threadIdx.x == 0 && blockIdx.x == 0) {
    int allz = 1;
    for (int i = 1; i < 128; i += 2)
      if (ei[i] != 0) { allz = 0; break; }
    *flag = allz;
  }
}

// --- passA: bucket histogram via per-block LDS counters --------------------
__global__ __launch_bounds__(256) void passA_k(const void* ei, const int* __restrict__ flag,
                                               int* __restrict__ bucket_cnt, int E, int NB) {
  __shared__ int cnt[256];
  int t = threadIdx.x;
  cnt[t] = 0;
  __syncthreads();
  int is64 = *flag;
  for (int e = blockIdx.x * 256 + t; e < E; e += gridDim.x * 256) {
    int c = eidx(ei, (size_t)E + e, is64);
    atomicAdd(&cnt[c >> 9], 1);
  }
  __syncthreads();
  if (t < NB && cnt[t]) atomicAdd(&bucket_cnt[t], cnt[t]);
}

// --- bscan: exclusive scan of bucket_cnt -> bucket_offs; init gcursor ------
__global__ __launch_bounds__(256) void bscan_k(const int* __restrict__ bucket_cnt,
                                               int* __restrict__ bucket_offs,
                                               int* __restrict__ gcursor, int NB) {
  __shared__ int sh[256];
  int t = threadIdx.x;
  int v = (t < NB) ? bucket_cnt[t] : 0;
  sh[t] = v;
  __syncthreads();
  for (int off = 1; off < 256; off <<= 1) {
    int x = (t >= off) ? sh[t - off] : 0;
    __syncthreads();
    sh[t] += x;
    __syncthreads();
  }
  if (t < NB) {
    int excl = sh[t] - v;
    bucket_offs[t] = excl;
    gcursor[t] = excl;
  }
  if (t == NB - 1) bucket_offs[NB] = sh[t];
}

// --- passB: partition edges into bucket-contiguous epk_binned --------------
// Each block: 4096-edge chunk -> LDS counting sort by bucket -> coalesced flush.
__global__ __launch_bounds__(256) void passB_k(const void* ei, const int* __restrict__ flag,
                                               int* __restrict__ gcursor,
                                               int2* __restrict__ epk_binned, int E, int NB) {
  __shared__ int2 sorted[4096];                       // 32 KB
  __shared__ int cnt[256], bbase[256], gb[256], cur[256];
  const int t = threadIdx.x;
  const int base = blockIdx.x * 4096;
  const int CH = min(4096, E - base);
  const int is64 = *flag;

  cnt[t] = 0;
  __syncthreads();
  // phase 1: count buckets in this chunk
  for (int i = t; i < CH; i += 256) {
    int c = eidx(ei, (size_t)E + base + i, is64);
    atomicAdd(&cnt[c >> 9], 1);
  }
  __syncthreads();
  // phase 2: exclusive scan of cnt -> bbase (Hillis-Steele over 256)
  {
    int v = cnt[t];
    __shared__ int sh[256];
    sh[t] = v;
    __syncthreads();
    for (int off = 1; off < 256; off <<= 1) {
      int x = (t >= off) ? sh[t - off] : 0;
      __syncthreads();
      sh[t] += x;
      __syncthreads();
    }
    bbase[t] = sh[t] - v;
    // phase 3: reserve global space for this chunk's bucket runs
    gb[t] = (t < NB && v) ? atomicAdd(&gcursor[t], v) : 0;
    cur[t] = 0;
  }
  __syncthreads();
  // phase 4: place chunk edges into LDS sorted by bucket
  for (int i = t; i < CH; i += 256) {
    int r = eidx(ei, (size_t)base + i, is64);
    int c = eidx(ei, (size_t)E + base + i, is64);
    int b = c >> 9;
    int rank = atomicAdd(&cur[b], 1);
    sorted[bbase[b] + rank] = make_int2(r, c);
  }
  __syncthreads();
  // phase 5: flush linearly -> coalesced runs into each bucket's reservation
  for (int i = t; i < CH; i += 256) {
    int2 v = sorted[i];
    int b = v.y >> 9;
    epk_binned[gb[b] + (i - bbase[b])] = v;
  }
}

// --- passC0: per-bucket degree count -> deg[] and offs[] (coalesced) -------
__global__ __launch_bounds__(256) void passC0_k(const int2* __restrict__ epk_binned,
                                                const int* __restrict__ bucket_offs,
                                                int* __restrict__ deg, int* __restrict__ offs,
                                                int n, int NB) {
  __shared__ int dcnt[512];
  __shared__ int s[256];
  const int t = threadIdx.x;
  const int b = blockIdx.x;
  dcnt[t] = 0; dcnt[t + 256] = 0;
  __syncthreads();
  const int lo = bucket_offs[b], hi = bucket_offs[b + 1];
  for (int i = lo + t; i < hi; i += 256)
    atomicAdd(&dcnt[epk_binned[i].y & 511], 1);
  __syncthreads();
  // exclusive scan of dcnt[512] with 256 threads (pair-sum + Hillis-Steele)
  int d0 = dcnt[2 * t], d1 = dcnt[2 * t + 1];
  int pv = d0 + d1;
  s[t] = pv;
  __syncthreads();
  for (int off = 1; off < 256; off <<= 1) {
    int x = (t >= off) ? s[t - off] : 0;
    __syncthreads();
    s[t] += x;
    __syncthreads();
  }
  int pex = s[t] - pv;  // exclusive over pairs
  const int node0 = b << 9;
  int g0 = node0 + 2 * t, g1 = node0 + 2 * t + 1;
  if (g0 < n) { deg[g0] = d0; offs[g0] = lo + pex; }
  if (g1 < n) { deg[g1] = d1; offs[g1] = lo + pex + d0; }
  if (b == NB - 1 && t == 0) offs[n] = hi;
}

__global__ void dinv_k(const int* __restrict__ deg, float* __restrict__ dinv, int n) {
  int i = blockIdx.x * blockDim.x + threadIdx.x;
  if (i < n) dinv[i] = rsqrtf((float)deg[i] + 1.0f);  // +1 = self loop
}

// --- passC: final placement sorted by exact dest; pack (src, dinv[src]) ----
// One workgroup per bucket -> the bucket's epk region is written by ONE XCD,
// so cachelines assemble fully before writeback (no 64B/edge amplification).
__global__ __launch_bounds__(256) void passC_k(const int2* __restrict__ epk_binned,
                                               const int* __restrict__ bucket_offs,
                                               const int* __restrict__ offs,
                                               const float* __restrict__ dinv,
                                               int2* __restrict__ epk) {
  __shared__ int cur[512];
  const int t = threadIdx.x;
  const int b = blockIdx.x;
  cur[t] = 0; cur[t + 256] = 0;
  __syncthreads();
  const int lo = bucket_offs[b], hi = bucket_offs[b + 1];
  for (int i = lo + t; i < hi; i += 256) {
    int2 v = epk_binned[i];
    int pos = offs[v.y] + atomicAdd(&cur[v.y & 511], 1);
    epk[pos] = make_int2(v.x, __float_as_int(dinv[v.x]));
  }
}

// --- LDS-tiled SGEMM: H[N x COLS](bf16) = X[N x 128](f32) @ W[128 x COLS] --
template <int COLS>
__global__ __launch_bounds__(256) void gemm_k(const float* __restrict__ X,
                                              const float* __restrict__ W,
                                              uint16_t* __restrict__ H, int N) {
  constexpr int KB = 32;
  constexpr int CG = COLS / 8;
  constexpr int RG = 256 / CG;
  constexpr int ROWS = RG * 8;
  constexpr int XP = ROWS + 4;

  __shared__ float Xs[KB][XP];
  __shared__ float Ws[KB][COLS];

  const int tid = threadIdx.x;
  const int cg = tid % CG, rg = tid / CG;
  const int c0 = cg * 8, rr0 = rg * 8;
  const int rowbase = blockIdx.x * ROWS;

  float acc[8][8];
#pragma unroll
  for (int a = 0; a < 8; ++a)
#pragma unroll
    for (int b = 0; b < 8; ++b) acc[a][b] = 0.f;

  for (int k0 = 0; k0 < 128; k0 += KB) {
    __syncthreads();
#pragma unroll
    for (int i = tid; i < KB * (COLS / 4); i += 256) {
      int kk = i / (COLS / 4);
      int cc = i % (COLS / 4);
      float4 w = ((const float4*)(W + (size_t)(k0 + kk) * COLS))[cc];
      ((float4*)&Ws[kk][0])[cc] = w;
    }
#pragma unroll
    for (int i = tid; i < ROWS * (KB / 4); i += 256) {
      int rr = i / (KB / 4);
      int k4 = i % (KB / 4);
      int gr = rowbase + rr;
      if (gr >= N) gr = N - 1;
      float4 xv = ((const float4*)(X + (size_t)gr * 128 + k0))[k4];
      Xs[k4 * 4 + 0][rr] = xv.x;
      Xs[k4 * 4 + 1][rr] = xv.y;
      Xs[k4 * 4 + 2][rr] = xv.z;
      Xs[k4 * 4 + 3][rr] = xv.w;
    }
    __syncthreads();
#pragma unroll 2
    for (int k = 0; k < KB; ++k) {
      float4 xa = *(const float4*)&Xs[k][rr0];
      float4 xb = *(const float4*)&Xs[k][rr0 + 4];
      float4 wa = *(const float4*)&Ws[k][c0];
      float4 wb = *(const float4*)&Ws[k][c0 + 4];
      float xr[8] = {xa.x, xa.y, xa.z, xa.w, xb.x, xb.y, xb.z, xb.w};
      float wr[8] = {wa.x, wa.y, wa.z, wa.w, wb.x, wb.y, wb.z, wb.w};
#pragma unroll
      for (int a = 0; a < 8; ++a)
#pragma unroll
        for (int b = 0; b < 8; ++b) acc[a][b] = fmaf(xr[a], wr[b], acc[a][b]);
    }
  }
#pragma unroll
  for (int a = 0; a < 8; ++a) {
    int row = rowbase + rr0 + a;
    if (row < N) {
      uint32_t p[4];
#pragma unroll
      for (int q = 0; q < 4; ++q)
        p[q] = (uint32_t)f2bf(acc[a][2 * q]) | ((uint32_t)f2bf(acc[a][2 * q + 1]) << 16);
      uint4 ov = make_uint4(p[0], p[1], p[2], p[3]);
      *(uint4*)&H[(size_t)row * COLS + c0] = ov;
    }
  }
}

// Aggregate D=128 from bf16 H: one wave per node, 1 uint (2 bf16) per lane.
__global__ __launch_bounds__(256) void agg128_k(const uint32_t* __restrict__ H2,
                                                const int* __restrict__ offs,
                                                const int2* __restrict__ epk,
                                                const float* __restrict__ dinv,
                                                const float* __restrict__ bias,
                                                float* __restrict__ out,
                                                int relu, int N) {
  int wid = threadIdx.x >> 6;
  int lane = threadIdx.x & 63;
  int c = blockIdx.x * 4 + wid;
  if (c >= N) return;
  float ax = 0.f, ay = 0.f;
  int e0 = offs[c], e1 = offs[c + 1];
  int e = e0;
  for (; e + 4 <= e1; e += 4) {
    int2 p0 = epk[e], p1 = epk[e + 1], p2 = epk[e + 2], p3 = epk[e + 3];
    uint32_t v0 = H2[(size_t)p0.x * 64 + lane];
    uint32_t v1 = H2[(size_t)p1.x * 64 + lane];
    uint32_t v2 = H2[(size_t)p2.x * 64 + lane];
    uint32_t v3 = H2[(size_t)p3.x * 64 + lane];
    float w0 = __int_as_float(p0.y), w1 = __int_as_float(p1.y);
    float w2 = __int_as_float(p2.y), w3 = __int_as_float(p3.y);
    ax = fmaf(w0, __uint_as_float(v0 << 16), ax); ay = fmaf(w0, __uint_as_float(v0 & 0xffff0000u), ay);
    ax = fmaf(w1, __uint_as_float(v1 << 16), ax); ay = fmaf(w1, __uint_as_float(v1 & 0xffff0000u), ay);
    ax = fmaf(w2, __uint_as_float(v2 << 16), ax); ay = fmaf(w2, __uint_as_float(v2 & 0xffff0000u), ay);
    ax = fmaf(w3, __uint_as_float(v3 << 16), ax); ay = fmaf(w3, __uint_as_float(v3 & 0xffff0000u), ay);
  }
  for (; e < e1; ++e) {
    int2 p = epk[e];
    uint32_t v = H2[(size_t)p.x * 64 + lane];
    float w = __int_as_float(p.y);
    ax = fmaf(w, __uint_as_float(v << 16), ax);
    ay = fmaf(w, __uint_as_float(v & 0xffff0000u), ay);
  }
  float dc = dinv[c];
  uint32_t hv = H2[(size_t)c * 64 + lane];
  float rx = fmaf(dc, ax, dc * dc * __uint_as_float(hv << 16)) + bias[lane * 2];
  float ry = fmaf(dc, ay, dc * dc * __uint_as_float(hv & 0xffff0000u)) + bias[lane * 2 + 1];
  if (relu) { rx = fmaxf(rx, 0.f); ry = fmaxf(ry, 0.f); }
  float2 res; res.x = rx; res.y = ry;
  ((float2*)out)[(size_t)c * 64 + lane] = res;
}

// Aggregate D=64 from bf16 H: one wave per node, 1 ushort per lane.
__global__ __launch_bounds__(256) void agg64_k(const uint16_t* __restrict__ H,
                                               const int* __restrict__ offs,
                                               const int2* __restrict__ epk,
                                               const float* __restrict__ dinv,
                                               const float* __restrict__ bias,
                                               float* __restrict__ out,
                                               int relu, int N) {
  int wid = threadIdx.x >> 6;
  int lane = threadIdx.x & 63;
  int c = blockIdx.x * 4 + wid;
  if (c >= N) return;
  float acc = 0.f;
  int e0 = offs[c], e1 = offs[c + 1];
  int e = e0;
  for (; e + 4 <= e1; e += 4) {
    int2 p0 = epk[e], p1 = epk[e + 1], p2 = epk[e + 2], p3 = epk[e + 3];
    uint32_t v0 = H[(size_t)p0.x * 64 + lane];
    uint32_t v1 = H[(size_t)p1.x * 64 + lane];
    uint32_t v2 = H[(size_t)p2.x * 64 + lane];
    uint32_t v3 = H[(size_t)p3.x * 64 + lane];
    acc = fmaf(__int_as_float(p0.y), __uint_as_float(v0 << 16), acc);
    acc = fmaf(__int_as_float(p1.y), __uint_as_float(v1 << 16), acc);
    acc = fmaf(__int_as_float(p2.y), __uint_as_float(v2 << 16), acc);
    acc = fmaf(__int_as_float(p3.y), __uint_as_float(v3 << 16), acc);
  }
  for (; e < e1; ++e) {
    int2 p = epk[e];
    uint32_t v = H[(size_t)p.x * 64 + lane];
    acc = fmaf(__int_as_float(p.y), __uint_as_float(v << 16), acc);
  }
  float dc = dinv[c];
  uint32_t hv = H[(size_t)c * 64 + lane];
  float r = fmaf(dc, acc, dc * dc * __uint_as_float(hv << 16)) + bias[lane];
  if (relu) r = fmaxf(r, 0.f);
  out[(size_t)c * 64 + lane] = r;
}

extern "C" void kernel_launch(void* const* d_in, const int* in_sizes, int n_in,
                              void* d_out, int out_size, void* d_ws, size_t ws_size,
                              hipStream_t stream) {
  const float* x  = (const float*)d_in[0];
  const void*  ei = d_in[1];
  const float* W0 = (const float*)d_in[2];
  const float* b0 = (const float*)d_in[3];
  const float* W1 = (const float*)d_in[4];
  const float* b1 = (const float*)d_in[5];
  const float* W2 = (const float*)d_in[6];
  const float* b2 = (const float*)d_in[7];
  float* out = (float*)d_out;

  const int n = in_sizes[0] / 128;   // 100000
  const int E = in_sizes[1] / 2;     // 1600000
  const int NB = (n + 511) >> 9;     // 196 buckets of 512 nodes (NB <= 256)

  char* ws = (char*)d_ws;
  size_t off = 0;
  auto alloc = [&](size_t bytes) { char* p = ws + off; off = ws_align(off + bytes); return p; };
  int*      bucket_cnt  = (int*)alloc(256 * 4);
  int*      bucket_offs = (int*)alloc(257 * 4);
  int*      gcursor     = (int*)alloc(256 * 4);
  int*      deg         = (int*)alloc((size_t)n * 4);
  int*      offs        = (int*)alloc((size_t)(n + 1) * 4);
  float*    dinv        = (float*)alloc((size_t)n * 4);
  int*      flag        = (int*)alloc(4);
  int2*     epk_binned  = (int2*)alloc((size_t)E * 8);
  int2*     epk         = (int2*)alloc((size_t)E * 8);
  uint16_t* hbuf        = (uint16_t*)alloc((size_t)n * 128 * 2);  // bf16 gather payload
  float*    abuf        = (float*)alloc((size_t)n * 128 * 4);     // fp32 activations
  (void)ws_size;

  hipMemsetAsync(bucket_cnt, 0, 256 * 4, stream);

  detect_k<<<1, 64, 0, stream>>>((const int*)ei, flag);
  passA_k<<<512, 256, 0, stream>>>(ei, flag, bucket_cnt, E, NB);
  bscan_k<<<1, 256, 0, stream>>>(bucket_cnt, bucket_offs, gcursor, NB);
  passB_k<<<(E + 4095) / 4096, 256, 0, stream>>>(ei, flag, gcursor, epk_binned, E, NB);
  passC0_k<<<NB, 256, 0, stream>>>(epk_binned, bucket_offs, deg, offs, n, NB);
  dinv_k<<<(n + 255) / 256, 256, 0, stream>>>(deg, dinv, n);
  passC_k<<<NB, 256, 0, stream>>>(epk_binned, bucket_offs, offs, dinv, epk);

  int agg_blocks = (n + 3) / 4;

  // Layer 0
  gemm_k<128><<<(n + 127) / 128, 256, 0, stream>>>(x, W0, hbuf, n);
  agg128_k<<<agg_blocks, 256, 0, stream>>>((const uint32_t*)hbuf, offs, epk, dinv, b0, abuf, 1, n);
  // Layer 1
  gemm_k<128><<<(n + 127) / 128, 256, 0, stream>>>(abuf, W1, hbuf, n);
  agg128_k<<<agg_blocks, 256, 0, stream>>>((const uint32_t*)hbuf, offs, epk, dinv, b1, abuf, 1, n);
  // Layer 2 (no relu) -> d_out (fp32)
  gemm_k<64><<<(n + 255) / 256, 256, 0, stream>>>(abuf, W2, hbuf, n);
  agg64_k<<<agg_blocks, 256, 0, stream>>>(hbuf, offs, epk, dinv, b2, out, 0, n);
}